// Round 4
// baseline (52.091 us; speedup 1.0000x reference)
//
#include <hip/hip_runtime.h>
#include <math.h>

// Rolling population std, window W=64, per row of x[B=4096][T=8192] fp32.
// One 256-thread block per row. Row staged in a 32 KiB XOR-swizzled LDS
// buffer (exactly 5 blocks/CU); all LDS traffic is ds_read_b128 /
// ds_write_b128; per-thread sliding-window sums give O(1) work per output;
// results round-trip through the same LDS buffer for coalesced stores.
//
// R3 change: output stores are NON-TEMPORAL (nt flag). The 133 MB output
// stream otherwise evicts the 134 MB input from the 256 MiB L3 between
// graph replays (measured: FETCH_SIZE = half the input). nt stores keep
// the input L3-resident -> read side served from L3, writes stream to HBM.
//
// Swizzle (T2 / G4 pattern, dword units): d ^= ((d>>5)&7)<<2. Same
// involution on write and read.

constexpr int T     = 8192;
constexpr int W     = 64;
constexpr int OUTW  = T - W + 1;   // 8129
constexpr int NT    = 256;
constexpr int CHUNK = 32;          // outputs per thread

__global__ __launch_bounds__(NT, 5)
void MovingStandardDeviation_23682449670506_kernel(const float* __restrict__ x,
                                                   float* __restrict__ out) {
    __shared__ float lds[T];                 // 32768 B exactly
    const int t = threadIdx.x;
    const size_t b = blockIdx.x;
    const float* rowp = x + b * (size_t)T;

    // ---- Stage row into LDS: 8 x (global float4 load -> swizzled b128 write).
    {
        const int srow = (t >> 3) & 7;
        const int sb = (4 * t) ^ (srow << 2);
        #pragma unroll
        for (int i = 0; i < 8; ++i) {
            const float4 v = *reinterpret_cast<const float4*>(rowp + 4 * t + 1024 * i);
            *reinterpret_cast<float4*>(lds + sb + 1024 * i) = v;
        }
    }
    __syncthreads();

    // ---- Compute. Thread t owns outputs j0..j0+31, needs inputs j0..j0+95
    // as 3 groups of 8 float4s. Group bases clamped to 8160 so reads stay
    // in-bounds for t>=254 (those results are masked at store).
    const int j0  = t * CHUNK;
    const int bk0 = j0;                       // <= 8160, never clamped
    const int bk1 = min(j0 + 32, T - 32);
    const int bk2 = min(j0 + 64, T - 32);

    float4 q[8];                              // kept: x[j0..j0+31] (xout source)
    {
        const int r0 = (bk0 >> 5) & 7;
        const int A0 = bk0 + (r0 << 2);
        #pragma unroll
        for (int c = 0; c < 8; ++c)
            q[c] = *reinterpret_cast<const float4*>(lds + (A0 ^ (c << 2)));
    }

    float s1, s2;
    {
        float a0 = 0.f, a1 = 0.f, a2 = 0.f, a3 = 0.f;
        float b0 = 0.f, b1 = 0.f, b2 = 0.f, b3 = 0.f;
        #pragma unroll
        for (int c = 0; c < 8; ++c) {
            a0 += q[c].x; b0 = fmaf(q[c].x, q[c].x, b0);
            a1 += q[c].y; b1 = fmaf(q[c].y, q[c].y, b1);
            a2 += q[c].z; b2 = fmaf(q[c].z, q[c].z, b2);
            a3 += q[c].w; b3 = fmaf(q[c].w, q[c].w, b3);
        }
        const int r1 = (bk1 >> 5) & 7;
        const int A1 = bk1 + (r1 << 2);
        #pragma unroll
        for (int c = 0; c < 8; ++c) {
            const float4 v = *reinterpret_cast<const float4*>(lds + (A1 ^ (c << 2)));
            a0 += v.x; b0 = fmaf(v.x, v.x, b0);
            a1 += v.y; b1 = fmaf(v.y, v.y, b1);
            a2 += v.z; b2 = fmaf(v.z, v.z, b2);
            a3 += v.w; b3 = fmaf(v.w, v.w, b3);
        }
        s1 = (a0 + a1) + (a2 + a3);
        s2 = (b0 + b1) + (b2 + b3);
    }

    float res[CHUNK];                         // compile-time-const indexed only
    const float invw = 1.0f / (float)W;
    {
        const float mean = s1 * invw;
        res[0] = sqrtf(fmaxf(fmaf(-mean, mean, s2 * invw), 0.f));
    }
    {
        const int r2 = (bk2 >> 5) & 7;
        const int A2 = bk2 + (r2 << 2);
        #pragma unroll
        for (int c = 0; c < 8; ++c) {
            const float4 vin = *reinterpret_cast<const float4*>(lds + (A2 ^ (c << 2)));
            #pragma unroll
            for (int e = 0; e < 4; ++e) {
                const int jj = 4 * c + e + 1;          // 1..32
                if (jj < CHUNK) {
                    const float xin  = (e == 0) ? vin.x : (e == 1) ? vin.y
                                     : (e == 2) ? vin.z : vin.w;
                    const int p = jj - 1;              // 0..30
                    const float4 qq = q[p >> 2];
                    const float xout = ((p & 3) == 0) ? qq.x : ((p & 3) == 1) ? qq.y
                                     : ((p & 3) == 2) ? qq.z : qq.w;
                    const float d = xin - xout;
                    s1 += d;
                    s2 = fmaf(d, xin + xout, s2);
                    const float mean = s1 * invw;
                    res[jj] = sqrtf(fmaxf(fmaf(-mean, mean, s2 * invw), 0.f));
                }
            }
        }
    }
    __syncthreads();

    // ---- Transpose: res -> own j0 region of LDS (float offset 32*t),
    // swizzled b128 writes. swz(32t+4c) = (32t + ((t&7)<<2)) ^ (c<<2).
    {
        const int A = 32 * t + ((t & 7) << 2);
        #pragma unroll
        for (int c = 0; c < 8; ++c) {
            const float4 v = make_float4(res[4 * c], res[4 * c + 1],
                                         res[4 * c + 2], res[4 * c + 3]);
            *reinterpret_cast<float4*>(lds + (A ^ (c << 2))) = v;
        }
    }
    __syncthreads();

    // ---- Coalesced scalar NON-TEMPORAL stores. d = t + 256 i.
    {
        const int srow = (t >> 5) & 7;
        const int base = t ^ (srow << 2);
        float* orow = out + b * (size_t)OUTW;
        #pragma unroll
        for (int i = 0; i < 32; ++i) {
            const int j = t + 256 * i;
            const float f = lds[base + 256 * i];
            if (j < OUTW) __builtin_nontemporal_store(f, orow + j);
        }
    }
}

extern "C" void kernel_launch(void* const* d_in, const int* in_sizes, int n_in,
                              void* d_out, int out_size, void* d_ws, size_t ws_size,
                              hipStream_t stream) {
    const float* x = (const float*)d_in[0];
    float* out = (float*)d_out;
    const int B = in_sizes[0] / T;  // 4096
    MovingStandardDeviation_23682449670506_kernel<<<B, NT, 0, stream>>>(x, out);
}

// Round 5
// 47.655 us; speedup vs baseline: 1.0931x; 1.0931x over previous
//
#include <hip/hip_runtime.h>
#include <math.h>

// Rolling population std, window W=64, per row of x[B=4096][T=8192] fp32.
//
// R5: TWO blocks per row (half-row each, 64-float halo) -> LDS = 4160 floats
// = 16.6 KiB -> 8 blocks/CU = 32/32 waves (was 5 blocks / 20 waves at 32 KiB).
// nt stores REVERTED (R4: WRITE_SIZE 130->146 MB, dur +12% -- nt writes at
// worse HBM granularity on gfx950).
//
// Per 256-thread block: stage 4160 floats XOR-swizzled, b128 LDS traffic
// only; each thread slides a 64-window over its 16 outputs (O(1)/output);
// results transpose through the same LDS for fully-coalesced scalar stores.
// Swizzle (dword units): d ^= ((d>>5)&7)<<2, same involution on both sides.

constexpr int T     = 8192;
constexpr int W     = 64;
constexpr int OUTW  = T - W + 1;   // 8129
constexpr int NT    = 256;
constexpr int HALF  = 4096;        // outputs per block
constexpr int STAGE = 4160;        // floats staged = HALF + W

__global__ __launch_bounds__(NT, 8)
void MovingStandardDeviation_23682449670506_kernel(const float* __restrict__ x,
                                                   float* __restrict__ out) {
    __shared__ float lds[STAGE];             // 16640 B
    const int t = threadIdx.x;
    const int h = blockIdx.x & 1;            // row half
    const size_t b = blockIdx.x >> 1;
    const int base = h * HALF;               // global col of local 0
    const float* rowp = x + b * (size_t)T;

    // ---- Stage [base, base+STAGE) into LDS (src clamped to row end; the
    // over-staged floats for h=1 only feed masked outputs).
    {
        const int rx = ((t >> 3) & 7) << 2;
        #pragma unroll
        for (int l = 0; l < 4; ++l) {
            const int e = 4 * t + 1024 * l;          // dst float idx
            const int src = min(base + e, T - 4);
            const float4 v = *reinterpret_cast<const float4*>(rowp + src);
            *reinterpret_cast<float4*>(lds + (e ^ rx)) = v;
        }
        if (t < 16) {
            const int e = 4096 + 4 * t;
            const int src = min(base + e, T - 4);
            const float4 v = *reinterpret_cast<const float4*>(rowp + src);
            *reinterpret_cast<float4*>(lds + (e ^ rx)) = v;
        }
    }
    __syncthreads();

    // ---- Compute: thread t owns local outputs [16t, 16t+16), reads local
    // inputs [16t, 16t+80) as 5 groups of 4 float4s. All in-bounds (<=4156).
    const int j0l = 16 * t;

    float4 q[4];                              // x[j0l..j0l+15]: xout source
    {
        const int rxg = ((j0l >> 5) & 7) << 2;
        #pragma unroll
        for (int c = 0; c < 4; ++c)
            q[c] = *reinterpret_cast<const float4*>(lds + ((j0l + 4 * c) ^ rxg));
    }

    float s1, s2;
    {
        float a0 = 0.f, a1 = 0.f, a2 = 0.f, a3 = 0.f;
        float b0 = 0.f, b1 = 0.f, b2 = 0.f, b3 = 0.f;
        #pragma unroll
        for (int c = 0; c < 4; ++c) {
            a0 += q[c].x; b0 = fmaf(q[c].x, q[c].x, b0);
            a1 += q[c].y; b1 = fmaf(q[c].y, q[c].y, b1);
            a2 += q[c].z; b2 = fmaf(q[c].z, q[c].z, b2);
            a3 += q[c].w; b3 = fmaf(q[c].w, q[c].w, b3);
        }
        #pragma unroll
        for (int gi = 1; gi < 4; ++gi) {
            const int g = j0l + 16 * gi;
            const int rxg = ((g >> 5) & 7) << 2;
            #pragma unroll
            for (int c = 0; c < 4; ++c) {
                const float4 v = *reinterpret_cast<const float4*>(lds + ((g + 4 * c) ^ rxg));
                a0 += v.x; b0 = fmaf(v.x, v.x, b0);
                a1 += v.y; b1 = fmaf(v.y, v.y, b1);
                a2 += v.z; b2 = fmaf(v.z, v.z, b2);
                a3 += v.w; b3 = fmaf(v.w, v.w, b3);
            }
        }
        s1 = (a0 + a1) + (a2 + a3);
        s2 = (b0 + b1) + (b2 + b3);
    }

    float res[16];                            // compile-time-const indexed only
    const float invw = 1.0f / (float)W;
    {
        const float mean = s1 * invw;
        res[0] = sqrtf(fmaxf(fmaf(-mean, mean, s2 * invw), 0.f));
    }
    {
        const int g4 = j0l + 64;
        const int rx4 = ((g4 >> 5) & 7) << 2;
        #pragma unroll
        for (int c = 0; c < 4; ++c) {
            const float4 vin = *reinterpret_cast<const float4*>(lds + ((g4 + 4 * c) ^ rx4));
            #pragma unroll
            for (int e = 0; e < 4; ++e) {
                const int jj = 4 * c + e + 1;          // 1..16
                if (jj < 16) {
                    const float xin  = (e == 0) ? vin.x : (e == 1) ? vin.y
                                     : (e == 2) ? vin.z : vin.w;
                    const float4 qq = q[c];            // xout = x[j0l + jj - 1]
                    const float xout = (e == 0) ? qq.x : (e == 1) ? qq.y
                                     : (e == 2) ? qq.z : qq.w;
                    const float d = xin - xout;
                    s1 += d;
                    s2 = fmaf(d, xin + xout, s2);
                    const float mean = s1 * invw;
                    res[jj] = sqrtf(fmaxf(fmaf(-mean, mean, s2 * invw), 0.f));
                }
            }
        }
    }
    __syncthreads();

    // ---- Transpose res -> lds[16t..16t+15], swizzled b128 writes.
    // d = 16t + 4c -> d>>5 = t>>1 (no carries: low 4 bits of 16t are 0).
    {
        const int rxw = ((t >> 1) & 7) << 2;
        #pragma unroll
        for (int c = 0; c < 4; ++c) {
            const float4 v = make_float4(res[4 * c], res[4 * c + 1],
                                         res[4 * c + 2], res[4 * c + 3]);
            *reinterpret_cast<float4*>(lds + ((16 * t + 4 * c) ^ rxw)) = v;
        }
    }
    __syncthreads();

    // ---- Coalesced scalar stores of local outputs [0, 4096), masked to
    // the row's valid range. d = t + 256 i -> row (t>>5)&7, i-independent.
    {
        const int sbase = t ^ (((t >> 5) & 7) << 2);
        float* orow = out + b * (size_t)OUTW + base;
        const int lim = OUTW - base;          // 8129 (h=0) or 4033 (h=1)
        #pragma unroll
        for (int i = 0; i < 16; ++i) {
            const int j = t + 256 * i;
            const float f = lds[sbase + 256 * i];
            if (j < lim) orow[j] = f;
        }
    }
}

extern "C" void kernel_launch(void* const* d_in, const int* in_sizes, int n_in,
                              void* d_out, int out_size, void* d_ws, size_t ws_size,
                              hipStream_t stream) {
    const float* x = (const float*)d_in[0];
    float* out = (float*)d_out;
    const int B = in_sizes[0] / T;  // 4096
    MovingStandardDeviation_23682449670506_kernel<<<2 * B, NT, 0, stream>>>(x, out);
}

// Round 6
// 46.551 us; speedup vs baseline: 1.1190x; 1.0237x over previous
//
#include <hip/hip_runtime.h>
#include <math.h>

// Rolling population std, window W=64, per row of x[B=4096][T=8192] fp32.
// One 256-thread block per row. Row staged in a 32 KiB XOR-swizzled LDS
// buffer (exactly 5 blocks/CU); all LDS traffic is ds_read_b128 /
// ds_write_b128; per-thread sliding-window sums give O(1) work per output;
// results round-trip through the same LDS buffer for coalesced stores.
//
// FINAL (R6 = revert to R3's measured-best 46.5 us):
//  - R4 nt stores: REGRESSED (+12%, WRITE_SIZE 130->146 MB) -> reverted.
//  - R5 half-row/8-blocks-per-CU: occupancy 33->65% with FLAT duration ->
//    not latency-bound; reverted.
// Traffic is minimal (FETCH = half-input, L3 serves the rest; WRITE exact),
// 4.2 TB/s effective mixed-stream = this op's practical ceiling.
//
// Swizzle (T2 / G4 pattern, dword units): d ^= ((d>>5)&7)<<2. Same
// involution on write and read.

constexpr int T     = 8192;
constexpr int W     = 64;
constexpr int OUTW  = T - W + 1;   // 8129
constexpr int NT    = 256;
constexpr int CHUNK = 32;          // outputs per thread

__global__ __launch_bounds__(NT, 5)
void MovingStandardDeviation_23682449670506_kernel(const float* __restrict__ x,
                                                   float* __restrict__ out) {
    __shared__ float lds[T];                 // 32768 B exactly
    const int t = threadIdx.x;
    const size_t b = blockIdx.x;
    const float* rowp = x + b * (size_t)T;

    // ---- Stage row into LDS: 8 x (global float4 load -> swizzled b128 write).
    {
        const int srow = (t >> 3) & 7;
        const int sb = (4 * t) ^ (srow << 2);
        #pragma unroll
        for (int i = 0; i < 8; ++i) {
            const float4 v = *reinterpret_cast<const float4*>(rowp + 4 * t + 1024 * i);
            *reinterpret_cast<float4*>(lds + sb + 1024 * i) = v;
        }
    }
    __syncthreads();

    // ---- Compute. Thread t owns outputs j0..j0+31, needs inputs j0..j0+95
    // as 3 groups of 8 float4s. Group bases clamped to 8160 so reads stay
    // in-bounds for t>=254 (those results are masked at store).
    const int j0  = t * CHUNK;
    const int bk0 = j0;                       // <= 8160, never clamped
    const int bk1 = min(j0 + 32, T - 32);
    const int bk2 = min(j0 + 64, T - 32);

    float4 q[8];                              // kept: x[j0..j0+31] (xout source)
    {
        const int r0 = (bk0 >> 5) & 7;
        const int A0 = bk0 + (r0 << 2);
        #pragma unroll
        for (int c = 0; c < 8; ++c)
            q[c] = *reinterpret_cast<const float4*>(lds + (A0 ^ (c << 2)));
    }

    float s1, s2;
    {
        float a0 = 0.f, a1 = 0.f, a2 = 0.f, a3 = 0.f;
        float b0 = 0.f, b1 = 0.f, b2 = 0.f, b3 = 0.f;
        #pragma unroll
        for (int c = 0; c < 8; ++c) {
            a0 += q[c].x; b0 = fmaf(q[c].x, q[c].x, b0);
            a1 += q[c].y; b1 = fmaf(q[c].y, q[c].y, b1);
            a2 += q[c].z; b2 = fmaf(q[c].z, q[c].z, b2);
            a3 += q[c].w; b3 = fmaf(q[c].w, q[c].w, b3);
        }
        const int r1 = (bk1 >> 5) & 7;
        const int A1 = bk1 + (r1 << 2);
        #pragma unroll
        for (int c = 0; c < 8; ++c) {
            const float4 v = *reinterpret_cast<const float4*>(lds + (A1 ^ (c << 2)));
            a0 += v.x; b0 = fmaf(v.x, v.x, b0);
            a1 += v.y; b1 = fmaf(v.y, v.y, b1);
            a2 += v.z; b2 = fmaf(v.z, v.z, b2);
            a3 += v.w; b3 = fmaf(v.w, v.w, b3);
        }
        s1 = (a0 + a1) + (a2 + a3);
        s2 = (b0 + b1) + (b2 + b3);
    }

    float res[CHUNK];                         // compile-time-const indexed only
    const float invw = 1.0f / (float)W;
    {
        const float mean = s1 * invw;
        res[0] = sqrtf(fmaxf(fmaf(-mean, mean, s2 * invw), 0.f));
    }
    {
        const int r2 = (bk2 >> 5) & 7;
        const int A2 = bk2 + (r2 << 2);
        #pragma unroll
        for (int c = 0; c < 8; ++c) {
            const float4 vin = *reinterpret_cast<const float4*>(lds + (A2 ^ (c << 2)));
            #pragma unroll
            for (int e = 0; e < 4; ++e) {
                const int jj = 4 * c + e + 1;          // 1..32
                if (jj < CHUNK) {
                    const float xin  = (e == 0) ? vin.x : (e == 1) ? vin.y
                                     : (e == 2) ? vin.z : vin.w;
                    const int p = jj - 1;              // 0..30
                    const float4 qq = q[p >> 2];
                    const float xout = ((p & 3) == 0) ? qq.x : ((p & 3) == 1) ? qq.y
                                     : ((p & 3) == 2) ? qq.z : qq.w;
                    const float d = xin - xout;
                    s1 += d;
                    s2 = fmaf(d, xin + xout, s2);
                    const float mean = s1 * invw;
                    res[jj] = sqrtf(fmaxf(fmaf(-mean, mean, s2 * invw), 0.f));
                }
            }
        }
    }
    __syncthreads();

    // ---- Transpose: res -> own j0 region of LDS (float offset 32*t),
    // swizzled b128 writes. swz(32t+4c) = (32t + ((t&7)<<2)) ^ (c<<2).
    {
        const int A = 32 * t + ((t & 7) << 2);
        #pragma unroll
        for (int c = 0; c < 8; ++c) {
            const float4 v = make_float4(res[4 * c], res[4 * c + 1],
                                         res[4 * c + 2], res[4 * c + 3]);
            *reinterpret_cast<float4*>(lds + (A ^ (c << 2))) = v;
        }
    }
    __syncthreads();

    // ---- Coalesced scalar stores. d = t + 256 i; row = (t>>5)&7 const.
    {
        const int srow = (t >> 5) & 7;
        const int base = t ^ (srow << 2);
        float* orow = out + b * (size_t)OUTW;
        #pragma unroll
        for (int i = 0; i < 32; ++i) {
            const int j = t + 256 * i;
            const float f = lds[base + 256 * i];
            if (j < OUTW) orow[j] = f;
        }
    }
}

extern "C" void kernel_launch(void* const* d_in, const int* in_sizes, int n_in,
                              void* d_out, int out_size, void* d_ws, size_t ws_size,
                              hipStream_t stream) {
    const float* x = (const float*)d_in[0];
    float* out = (float*)d_out;
    const int B = in_sizes[0] / T;  // 4096
    MovingStandardDeviation_23682449670506_kernel<<<B, NT, 0, stream>>>(x, out);
}